// Round 12
// baseline (1029.329 us; speedup 1.0000x reference)
//
#include <hip/hip_runtime.h>
#include <cmath>
#include <cstdint>

typedef _Float16 f16;
typedef _Float16 half8 __attribute__((ext_vector_type(8)));
typedef _Float16 half4 __attribute__((ext_vector_type(4)));
typedef float f32x4 __attribute__((ext_vector_type(4)));
typedef int i32x4 __attribute__((ext_vector_type(4)));
typedef int8_t c16v __attribute__((ext_vector_type(16)));
typedef int8_t c4v __attribute__((ext_vector_type(4)));

#define M_TOTAL 32768     // B * C * T = 8 * 4096
#define D_MODEL 768
#define NE_TOT  25165824  // M_TOTAL * D_MODEL
#define SPREAD_STRIDE 16  // unsigneds between atomic cells (64 B: own cache line)

// ---------------------------------------------------------------- utilities

__device__ __forceinline__ void async_copy16(void* lds, const void* gmem) {
  __builtin_amdgcn_global_load_lds(
      (__attribute__((address_space(1))) void*)gmem,
      (__attribute__((address_space(3))) void*)lds, 16, 0, 0);
}

// gelu with A&S 7.1.26 erf approx: |erf err| <= 1.5e-7 (far below the f16
// rounding of the stored result). ~16 VALU ops vs ~35 for libm erff.
__device__ __forceinline__ float gelu_fast(float v) {
  float x = v * 0.70710678118654752f;
  float ax = fabsf(x);
  float t = __builtin_amdgcn_rcpf(fmaf(0.3275911f, ax, 1.0f));
  float y = t * (0.254829592f +
            t * (-0.284496736f +
            t * (1.421413741f +
            t * (-1.453152027f + t * 1.061405429f))));
  float e = __expf(-x * x);
  float erf_ax = fmaf(-y, e, 1.0f);
  float erf_x = copysignf(erf_ax, x);
  return 0.5f * v * (1.0f + erf_x);
}

__device__ __forceinline__ float slot_scale(const unsigned* slot) {
  return fmaxf(__uint_as_float(*slot), 1e-8f) / 127.0f;
}

__device__ __forceinline__ int8_t q8_val(float v, float s) {
  float q = fminf(fmaxf(rintf(v / s), -128.f), 127.f);
  return (int8_t)(int)q;
}

// NW-wave block max reduction
template <int NW>
__device__ __forceinline__ float block_reduce_max_t(float m) {
  __shared__ float red_brm[NW];
  for (int o = 32; o; o >>= 1) m = fmaxf(m, __shfl_down(m, o));
  int lane = threadIdx.x & 63, wv = threadIdx.x >> 6;
  if (lane == 0) red_brm[wv] = m;
  __syncthreads();
  float r = red_brm[0];
#pragma unroll
  for (int w = 1; w < NW; ++w) r = fmaxf(r, red_brm[w]);
  return r;
}

__device__ __forceinline__ unsigned* spread_cell(unsigned* spread, int slot,
                                                 int cell) {
  return spread + slot * 64 * SPREAD_STRIDE + (cell & 63) * SPREAD_STRIDE;
}

// XCD-chunked bijective swizzle (requires nwg % 8 == 0 — all our grids are).
__device__ __forceinline__ int xcd_swizzle(int lin, int nwg) {
  return (lin & 7) * (nwg >> 3) + (lin >> 3);
}

// 16 residual loads (4 rows x 4 col-tiles) into named registers — issued
// back-to-back so they batch in the memory pipe. Caller software-pipelines
// these ahead of the stores (resid may alias outf: fc2 is in-place, so no
// __restrict__ — batching must be structural, not alias-based).
__device__ __forceinline__ void load_resid16(const float* resid, int N,
                                             int r0, int c0, float* rv) {
#pragma unroll
  for (int j = 0; j < 4; ++j)
#pragma unroll
    for (int reg = 0; reg < 4; ++reg)
      rv[j * 4 + reg] = resid[(size_t)(r0 + reg) * N + c0 + j * 16];
}

// ---------------------------------------------------------------- small kernels

__global__ void zero_spread_k(unsigned* s) {
  int i = blockIdx.x * blockDim.x + threadIdx.x;
  if (i < 8 * 64 * SPREAD_STRIDE) s[i] = 0u;
}

__global__ void reduce_slots_k(const unsigned* __restrict__ spread,
                               unsigned* __restrict__ finals, int slot_lo,
                               int n_slots) {
  int wv = threadIdx.x >> 6, lane = threadIdx.x & 63;
  if (wv >= n_slots) return;
  int slot = slot_lo + wv;
  float m = __uint_as_float(spread[slot * 64 * SPREAD_STRIDE + lane * SPREAD_STRIDE]);
  for (int o = 32; o; o >>= 1) m = fmaxf(m, __shfl_down(m, o));
  if (lane == 0) finals[slot] = __float_as_uint(m);
}

__global__ __launch_bounds__(256) void absmax_k(const float* __restrict__ x,
                                                int n4, unsigned* spread,
                                                int slot) {
  int i = blockIdx.x * blockDim.x + threadIdx.x;
  int stride = gridDim.x * blockDim.x;
  float m = 0.f;
  const float4* x4 = (const float4*)x;
  for (; i < n4; i += stride) {
    float4 v = x4[i];
    m = fmaxf(m, fmaxf(fmaxf(fabsf(v.x), fabsf(v.y)),
                       fmaxf(fabsf(v.z), fabsf(v.w))));
  }
  m = block_reduce_max_t<4>(m);
  if (threadIdx.x == 0)
    atomicMax(spread_cell(spread, slot, blockIdx.x), __float_as_uint(m));
}

// weights: f32 -> int8 (4/thread)
__global__ void quant_w8_k(const float* __restrict__ x, int n4,
                           const unsigned* __restrict__ slot,
                           int8_t* __restrict__ out) {
  int i = blockIdx.x * blockDim.x + threadIdx.x;
  if (i >= n4) return;
  float s = slot_scale(slot);
  float4 v = ((const float4*)x)[i];
  c4v q = {q8_val(v.x, s), q8_val(v.y, s), q8_val(v.z, s), q8_val(v.w, s)};
  ((c4v*)out)[i] = q;
}

// LayerNorm: wave-per-row (4 rows/block), float4 loads (16 B/lane), half4
// stores, wave-only butterfly reductions — no LDS, no __syncthreads.
__global__ __launch_bounds__(256) void ln_k(const float* __restrict__ x,
                                            const float* __restrict__ gw,
                                            const float* __restrict__ bw,
                                            f16* __restrict__ out,
                                            unsigned* spread, int slot) {
  int tid = threadIdx.x, lane = tid & 63, wv = tid >> 6;
  int row = blockIdx.x * 4 + wv;
  const float4* xr = (const float4*)(x + (size_t)row * D_MODEL);
  float4 v[3];
  float s = 0.f, ss = 0.f;
#pragma unroll
  for (int j = 0; j < 3; ++j) {
    v[j] = xr[lane + j * 64];
    s += v[j].x + v[j].y + v[j].z + v[j].w;
    ss += v[j].x * v[j].x + v[j].y * v[j].y + v[j].z * v[j].z +
          v[j].w * v[j].w;
  }
#pragma unroll
  for (int o = 32; o; o >>= 1) {
    s += __shfl_xor(s, o);
    ss += __shfl_xor(ss, o);
  }
  float mean = s * (1.f / 768.f);
  float var = ss * (1.f / 768.f) - mean * mean;
  float rstd = rsqrtf(var + 1e-5f);
  const float4* g4 = (const float4*)gw;
  const float4* b4 = (const float4*)bw;
  f16* outr = out + (size_t)row * D_MODEL;
  float m = 0.f;
#pragma unroll
  for (int j = 0; j < 3; ++j) {
    float4 g = g4[lane + j * 64], b = b4[lane + j * 64];
    float y0 = (v[j].x - mean) * rstd * g.x + b.x;
    float y1 = (v[j].y - mean) * rstd * g.y + b.y;
    float y2 = (v[j].z - mean) * rstd * g.z + b.z;
    float y3 = (v[j].w - mean) * rstd * g.w + b.w;
    half4 hq = {(f16)y0, (f16)y1, (f16)y2, (f16)y3};
    *(half4*)(outr + (size_t)(lane + j * 64) * 4) = hq;
    m = fmaxf(m, fmaxf(fmaxf(fabsf(y0), fabsf(y1)),
                       fmaxf(fabsf(y2), fabsf(y3))));
  }
#pragma unroll
  for (int o = 32; o; o >>= 1) m = fmaxf(m, __shfl_xor(m, o));
  if (lane == 0)
    atomicMax(spread_cell(spread, slot, blockIdx.x * 4 + wv),
              __float_as_uint(m));
}

// ---------------------------------------------------------------- int8 GEMM
// C[m,n] = (sum_k q(A)[m,k]*qB[n,k]) * sA*sB + bias[n] (+resid) (+gelu).
// THIS ROUND (fused activation quantization): A is read as F16 and quantized
// IN-STAGING with the global per-tensor scale (computed by the producer's
// absmax epilogue) — eliminates the 4 standalone quant passes (526 MB of
// pure HBM round-trips ≈ 100 us; chip-wide VALU cost of the quant itself is
// only ~8 us). Path per A-chunk: 2x global_load_dwordx4 (f16, coalesced,
// reg-double-buffered 2 steps deep) -> cvt/scale/rint/clamp -> ds_write_b128
// into the SAME paired-row conflict-free layout (r9/r11: 0 conflicts).
// Unlike r9's failed B-direct (scattered 16-row loads on the MFMA operand
// path), these are coalesced row reads buffered through LDS.
// B stays int8 via global_load_lds, 3-buffer depth-2. A-LDS needs only 2
// buffers (data lives in regs until just before use). LDS 2x16+3x8 = 56 KB
// -> 2 blocks/CU. VMEM FIFO/step: B(t+2)[1] + A(t+2)[4] -> counted
// s_waitcnt vmcnt(6) steady (newer-than-A(t) = B(t+1)+A(t+1)+B(t+2)),
// tails 5/0. BM=256 x BN=128, 512 threads, 4Mx2N waves, 64x64/wave.
// MODE: 0 = f16 out (qkv), 1 = gelu+f16+absmax (fc1), 2 = resid+f32 out
// (proj/fc2; fc2 aliases resid==outf, epilogue pipelines batched loads
// ahead of stores). Split so MODE 2's VGPRs don't cost MODE 0/1 occupancy.
template <int MODE>
__global__ __launch_bounds__(512) void gemm_q_t(
    const f16* __restrict__ A, int lda,
    const int8_t* __restrict__ B,
    const unsigned* __restrict__ slotA, const unsigned* __restrict__ slotB,
    const float* __restrict__ bias, const float* resid,
    float* outf, f16* outh, unsigned* spread, int slot,
    int N, int K) {
  __shared__ __attribute__((aligned(16))) int8_t sA[2][128 * 128];  // 256 A-rows (int8)
  __shared__ __attribute__((aligned(16))) int8_t sB[3][64 * 128];   // 128 B-rows
  int tid = threadIdx.x;
  int nwg = gridDim.x * gridDim.y;
  int lin = blockIdx.y * gridDim.x + blockIdx.x;
  int swz = xcd_swizzle(lin, nwg);
  int n0 = (swz % gridDim.x) * 128, m0 = (swz / gridDim.x) * 256;
  int lane = tid & 63, wv = tid >> 6;            // 8 waves
  int wm = (wv >> 1) * 64, wn = (wv & 1) * 64;   // 4M x 2N wave grid
  int lr = lane & 15, quad = lane >> 4;

  float sa = slot_scale(slotA);
  float inv = 1.0f / sa;

  i32x4 acc[4][4];
#pragma unroll
  for (int i = 0; i < 4; ++i)
#pragma unroll
    for (int j = 0; j < 4; ++j) acc[i][j] = i32x4{0, 0, 0, 0};

  // ---- A source (f16): 2 chunks/thread. chunk c=(pr,sl): g = sl^(pr&7) ->
  // matrix row 2pr+(g>>2), k-chunk g&3 (16 elems). Ptrs advance 64 elems
  // per issued step.
  auto mkA = [&](int c) {
    int pr = c >> 3, sl = c & 7, g = sl ^ (pr & 7);
    return A + (size_t)(m0 + 2 * pr + (g >> 2)) * lda + (g & 3) * 16;
  };
  const f16* pa0 = mkA(tid);
  const f16* pa1 = mkA(512 + tid);
  int la0 = tid * 16, la1 = (512 + tid) * 16;

  // ---- B staging (int8 gload_lds): 1 chunk/thread, same paired-row map.
  auto mkB = [&](int c) {
    int pr = c >> 3, sl = c & 7, g = sl ^ (pr & 7);
    return B + (size_t)(n0 + 2 * pr + (g >> 2)) * K + (g & 3) * 16;
  };
  const int8_t* sb0 = mkB(tid);
  auto gloadB = [&](int8_t* buf) {
    async_copy16(buf + la0, sb0);
    sb0 += 64;
  };

  // ---- A reg sets (2-deep): 4 float4 each (chunk0 lo/hi, chunk1 lo/hi)
  float4 ra0, ra1, ra2, ra3;   // set 0 (even steps)
  float4 rb0, rb1, rb2, rb3;   // set 1 (odd steps)
  auto issueA0 = [&]() {
    ra0 = *(const float4*)pa0; ra1 = *(const float4*)(pa0 + 8);
    ra2 = *(const float4*)pa1; ra3 = *(const float4*)(pa1 + 8);
    pa0 += 64; pa1 += 64;
  };
  auto issueA1 = [&]() {
    rb0 = *(const float4*)pa0; rb1 = *(const float4*)(pa0 + 8);
    rb2 = *(const float4*)pa1; rb3 = *(const float4*)(pa1 + 8);
    pa0 += 64; pa1 += 64;
  };
  auto q16 = [&](float4 lo, float4 hi) -> c16v {
    half8 h0 = *(half8*)&lo;
    half8 h1 = *(half8*)&hi;
    c16v q;
#pragma unroll
    for (int e = 0; e < 8; ++e) {
      float v0 = (float)h0[e] * inv;
      float v1 = (float)h1[e] * inv;
      q[e] = (int8_t)(int)fminf(fmaxf(rintf(v0), -128.f), 127.f);
      q[8 + e] = (int8_t)(int)fminf(fmaxf(rintf(v1), -128.f), 127.f);
    }
    return q;
  };

  // ---- hoisted LDS read offsets (paired-row layout inverse; 0 conflicts)
  int aoff[4], boff[4];
#pragma unroll
  for (int i = 0; i < 4; ++i) {
    int r = wm + i * 16 + lr, pr = r >> 1;
    aoff[i] = pr * 128 + (((((r & 1) << 2) | quad) ^ (pr & 7)) * 16);
    int rb = wn + i * 16 + lr, prb = rb >> 1;
    boff[i] = prb * 128 + (((((rb & 1) << 2) | quad) ^ (prb & 7)) * 16);
  }
  auto compute = [&](const int8_t* a_s, const int8_t* b_s) {
    i32x4 af[4], bfv[4];
#pragma unroll
    for (int i = 0; i < 4; ++i) af[i] = *(const i32x4*)&a_s[aoff[i]];
#pragma unroll
    for (int j = 0; j < 4; ++j) bfv[j] = *(const i32x4*)&b_s[boff[j]];
#pragma unroll
    for (int i = 0; i < 4; ++i)
#pragma unroll
      for (int j = 0; j < 4; ++j)
        acc[i][j] = __builtin_amdgcn_mfma_i32_16x16x64_i8(af[i], bfv[j],
                                                          acc[i][j], 0, 0, 0);
  };

  // ---- pipeline. Issue order: B(0),A(0),B(1),A(1) | per step t: B(t+2),
  // wait, quant+write A(t), issue A(t+2), lgkm, bar, compute, bar.
  int8_t* pb0 = sB[0];
  int8_t* pb1 = sB[1];
  int8_t* pb2 = sB[2];
  gloadB(pb0);
  issueA0();
  gloadB(pb1);
  issueA1();
  int nsteps = K >> 6;
  int pairs = nsteps >> 1;
  for (int S = 0; S < pairs; ++S) {
    bool lastp = (S == pairs - 1);
    // ---- step t0 = 2S (set0, A-lds 0, B pb0)
    if (!lastp) {
      gloadB(pb2);
      asm volatile("s_waitcnt vmcnt(6)" ::: "memory");
    } else {
      asm volatile("s_waitcnt vmcnt(5)" ::: "memory");
    }
    *(c16v*)&sA[0][la0] = q16(ra0, ra1);
    *(c16v*)&sA[0][la1] = q16(ra2, ra3);
    if (!lastp) issueA0();                      // A(t0+2) -> set0
    asm volatile("s_waitcnt lgkmcnt(0)" ::: "memory");
    __builtin_amdgcn_s_barrier();
    compute(sA[0], pb0);
    __builtin_amdgcn_s_barrier();
    // ---- step t0+1 (set1, A-lds 1, B pb1)
    if (!lastp) {
      gloadB(pb0);                              // B(t0+3) (old B(t0) done)
      asm volatile("s_waitcnt vmcnt(6)" ::: "memory");
    } else {
      asm volatile("s_waitcnt vmcnt(0)" ::: "memory");
    }
    *(c16v*)&sA[1][la0] = q16(rb0, rb1);
    *(c16v*)&sA[1][la1] = q16(rb2, rb3);
    if (!lastp) issueA1();                      // A(t0+3) -> set1
    asm volatile("s_waitcnt lgkmcnt(0)" ::: "memory");
    __builtin_amdgcn_s_barrier();
    compute(sA[1], pb1);
    __builtin_amdgcn_s_barrier();
    int8_t* t = pb0;  // (pb0,pb1,pb2) <- (pb2,pb0,pb1)
    pb0 = pb2;
    pb2 = pb1;
    pb1 = t;
  }

  float scale = sa * slot_scale(slotB);
  int r0 = m0 + wm + quad * 4, c0 = n0 + wn + lr;
  float bv[4];
#pragma unroll
  for (int j = 0; j < 4; ++j) bv[j] = bias[c0 + j * 16];
  // epilogue: C/D layout col=lane&15, row=quad*4+reg
  if (MODE == 2) {
    // software-pipelined: batch i+1's 16 loads issue BEFORE batch i's stores,
    // so the alias-forced program order never serializes load latency.
    float rvA[16], rvB[16];
    load_resid16(resid, N, r0, c0, rvA);
#pragma unroll
    for (int i = 0; i < 4; ++i) {
      float* curv = (i & 1) ? rvB : rvA;   // static after full unroll
      float* nxt = (i & 1) ? rvA : rvB;
      if (i < 3) load_resid16(resid, N, r0 + (i + 1) * 16, c0, nxt);
#pragma unroll
      for (int j = 0; j < 4; ++j)
#pragma unroll
        for (int reg = 0; reg < 4; ++reg) {
          size_t idx = (size_t)(r0 + i * 16 + reg) * N + c0 + j * 16;
          outf[idx] = (float)acc[i][j][reg] * scale + bv[j] + curv[j * 4 + reg];
        }
    }
  } else if (MODE == 1) {
    float lmax = 0.f;
#pragma unroll
    for (int i = 0; i < 4; ++i)
#pragma unroll
      for (int j = 0; j < 4; ++j)
#pragma unroll
        for (int reg = 0; reg < 4; ++reg) {
          size_t idx = (size_t)(r0 + i * 16 + reg) * N + c0 + j * 16;
          float v = gelu_fast((float)acc[i][j][reg] * scale + bv[j]);
          lmax = fmaxf(lmax, fabsf(v));
          outh[idx] = (f16)v;
        }
    float bm = block_reduce_max_t<8>(lmax);
    if (tid == 0)
      atomicMax(spread_cell(spread, slot, blockIdx.x + gridDim.x * blockIdx.y),
                __float_as_uint(bm));
  } else {
#pragma unroll
    for (int i = 0; i < 4; ++i)
#pragma unroll
      for (int j = 0; j < 4; ++j)
#pragma unroll
        for (int reg = 0; reg < 4; ++reg) {
          size_t idx = (size_t)(r0 + i * 16 + reg) * N + c0 + j * 16;
          outh[idx] = (f16)((float)acc[i][j][reg] * scale + bv[j]);
        }
  }
}

// ---------------------------------------------------------------- attention
// one block per (b,c,head). MFMA path: S = Q K^T (16x16x32 f16, wave = 16-row
// strip), register softmax (row lives on 16 lanes x 4 tiles), P -> LDS
// (C-layout -> A-layout transform), O = P V. O written over the Q slice.
__global__ __launch_bounds__(256) void attn_k(f16* __restrict__ qkv,
                                              unsigned* spread, int slot) {
  // stride 72 f16: rows stay 16B-aligned; ds_read_b128 fragments hit all 8
  // bank-phases evenly ((lr*9+quad)%8 uniform)
  __shared__ __attribute__((aligned(16))) f16 sQ[64 * 72];
  __shared__ __attribute__((aligned(16))) f16 sK[64 * 72];
  __shared__ __attribute__((aligned(16))) f16 sV[64 * 72];
  __shared__ __attribute__((aligned(16))) f16 sP[64 * 72];
  int tid = threadIdx.x, lane = tid & 63, wv = tid >> 6;
  int lr = lane & 15, quad = lane >> 4;
  int swz = xcd_swizzle(blockIdx.x, gridDim.x);  // 12 head-blocks of one
  int h = swz % 12, bc = swz / 12;               // (b,c) slab stay on one XCD
  size_t base = (size_t)bc * 64 * 2304;
  int qo = h * 64, ko = qo + 768, vo = qo + 1536;

#pragma unroll
  for (int p = 0; p < 2; ++p) {
    int idx = p * 256 + tid;     // 512 chunks of 8 f16
    int t = idx >> 3, d8 = idx & 7;
    size_t g = base + (size_t)t * 2304 + d8 * 8;
    *(half8*)&sQ[t * 72 + d8 * 8] = *(const half8*)(qkv + g + qo);
    *(half8*)&sK[t * 72 + d8 * 8] = *(const half8*)(qkv + g + ko);
    *(half8*)&sV[t * 72 + d8 * 8] = *(const half8*)(qkv + g + vo);
  }
  __syncthreads();

  // S = Q K^T: wave wv owns rows wv*16 .. wv*16+15; 4 col tiles j
  f32x4 acc[4];
#pragma unroll
  for (int j = 0; j < 4; ++j) acc[j] = f32x4{0.f, 0.f, 0.f, 0.f};
#pragma unroll
  for (int ks = 0; ks < 2; ++ks) {
    half8 aq = *(const half8*)&sQ[(wv * 16 + lr) * 72 + ks * 32 + quad * 8];
#pragma unroll
    for (int j = 0; j < 4; ++j) {
      half8 bk = *(const half8*)&sK[(j * 16 + lr) * 72 + ks * 32 + quad * 8];
      acc[j] = __builtin_amdgcn_mfma_f32_16x16x32_f16(aq, bk, acc[j], 0, 0, 0);
    }
  }

  // softmax: row (quad,reg) spans 16 lanes (lr) x 4 tiles (j)
  float pr[4][4];  // [j][reg]
#pragma unroll
  for (int reg = 0; reg < 4; ++reg) {
    float v0 = acc[0][reg] * 0.125f, v1 = acc[1][reg] * 0.125f;
    float v2 = acc[2][reg] * 0.125f, v3 = acc[3][reg] * 0.125f;
    float mx = fmaxf(fmaxf(v0, v1), fmaxf(v2, v3));
    for (int o = 8; o; o >>= 1) mx = fmaxf(mx, __shfl_xor(mx, o));
    float e0 = __expf(v0 - mx), e1 = __expf(v1 - mx);
    float e2 = __expf(v2 - mx), e3 = __expf(v3 - mx);
    float sum = e0 + e1 + e2 + e3;
    for (int o = 8; o; o >>= 1) sum += __shfl_xor(sum, o);
    float inv = 1.f / sum;
    pr[0][reg] = e0 * inv; pr[1][reg] = e1 * inv;
    pr[2][reg] = e2 * inv; pr[3][reg] = e3 * inv;
  }
  // P: C-layout -> natural row-major in LDS (scalar b16, ~2-way conflicts)
#pragma unroll
  for (int j = 0; j < 4; ++j)
#pragma unroll
    for (int reg = 0; reg < 4; ++reg)
      sP[(wv * 16 + quad * 4 + reg) * 72 + j * 16 + lr] = (f16)pr[j][reg];
  __syncthreads();

  // O = P V: A from sP rows (vector), B = V[s][d] column reads (scalar u16)
  f32x4 oacc[4];
#pragma unroll
  for (int j = 0; j < 4; ++j) oacc[j] = f32x4{0.f, 0.f, 0.f, 0.f};
#pragma unroll
  for (int ks = 0; ks < 2; ++ks) {
    half8 ap = *(const half8*)&sP[(wv * 16 + lr) * 72 + ks * 32 + quad * 8];
#pragma unroll
    for (int j = 0; j < 4; ++j) {
      half8 bv;
#pragma unroll
      for (int jj = 0; jj < 8; ++jj)
        bv[jj] = sV[(ks * 32 + quad * 8 + jj) * 72 + j * 16 + lr];
      oacc[j] = __builtin_amdgcn_mfma_f32_16x16x32_f16(ap, bv, oacc[j], 0, 0, 0);
    }
  }

  float lmax = 0.f;
#pragma unroll
  for (int j = 0; j < 4; ++j)
#pragma unroll
    for (int reg = 0; reg < 4; ++reg) {
      int m = wv * 16 + quad * 4 + reg;
      float v = oacc[j][reg];
      qkv[base + (size_t)m * 2304 + qo + j * 16 + lr] = (f16)v;
      lmax = fmaxf(lmax, fabsf(v));
    }
  lmax = block_reduce_max_t<4>(lmax);
  if (tid == 0)
    atomicMax(spread_cell(spread, slot, blockIdx.x), __float_as_uint(lmax));
}

// ---------------------------------------------------------------- launch

extern "C" void kernel_launch(void* const* d_in, const int* in_sizes, int n_in,
                              void* d_out, int out_size, void* d_ws,
                              size_t ws_size, hipStream_t stream) {
  (void)in_sizes; (void)n_in; (void)out_size; (void)ws_size;
  const float* x      = (const float*)d_in[0];
  const float* ln1_g  = (const float*)d_in[1];
  const float* ln1_b  = (const float*)d_in[2];
  const float* qkv_w  = (const float*)d_in[3];
  const float* qkv_b  = (const float*)d_in[4];
  const float* proj_w = (const float*)d_in[5];
  const float* proj_b = (const float*)d_in[6];
  const float* ln2_g  = (const float*)d_in[7];
  const float* ln2_b  = (const float*)d_in[8];
  const float* fc1_w  = (const float*)d_in[9];
  const float* fc1_b  = (const float*)d_in[10];
  const float* fc2_w  = (const float*)d_in[11];
  const float* fc2_b  = (const float*)d_in[12];
  float* out = (float*)d_out;

  char* ws = (char*)d_ws;
  unsigned* spread = (unsigned*)ws;                       // 8 x 64 cells x 64B
  unsigned* finals = (unsigned*)(ws + 8 * 64 * SPREAD_STRIDE * 4);
  int8_t* qkv_wq  = (int8_t*)(ws + 33280);                // int8 weights
  int8_t* proj_wq = qkv_wq + 1769472;
  int8_t* fc1_wq  = proj_wq + 589824;
  int8_t* fc2_wq  = fc1_wq + 2359296;
  // activations: hbuf = LN output (f16, 50 MB); big = qkv/attn (f16 2304-wide,
  // 151 MB) then gelu (f16 3072-wide, 201 MB) — proj is done before fc1
  // overwrites big. All activation quantization is fused into GEMM staging;
  // the a_i8/g_q int8 buffers of earlier rounds are gone. Total ws ~259 MB.
  f16* hbuf = (f16*)(fc2_wq + 2359296);
  f16* big  = (f16*)((char*)hbuf + 50331648);

  zero_spread_k<<<(8 * 64 * SPREAD_STRIDE + 255) / 256, 256, 0, stream>>>(spread);

  absmax_k<<<256, 256, 0, stream>>>(qkv_w, 1769472 / 4, spread, 1);
  absmax_k<<<256, 256, 0, stream>>>(proj_w, 589824 / 4, spread, 2);
  absmax_k<<<256, 256, 0, stream>>>(fc1_w, 2359296 / 4, spread, 3);
  absmax_k<<<256, 256, 0, stream>>>(fc2_w, 2359296 / 4, spread, 4);
  reduce_slots_k<<<1, 256, 0, stream>>>(spread, finals, 1, 4);
  quant_w8_k<<<(1769472 / 4 + 255) / 256, 256, 0, stream>>>(qkv_w, 1769472 / 4, finals + 1, qkv_wq);
  quant_w8_k<<<(589824 / 4 + 255) / 256, 256, 0, stream>>>(proj_w, 589824 / 4, finals + 2, proj_wq);
  quant_w8_k<<<(2359296 / 4 + 255) / 256, 256, 0, stream>>>(fc1_w, 2359296 / 4, finals + 3, fc1_wq);
  quant_w8_k<<<(2359296 / 4 + 255) / 256, 256, 0, stream>>>(fc2_w, 2359296 / 4, finals + 4, fc2_wq);

  // LN1 -> hbuf (f16) + absmax slot 0
  ln_k<<<8192, 256, 0, stream>>>(x, ln1_g, ln1_b, hbuf, spread, 0);
  reduce_slots_k<<<1, 64, 0, stream>>>(spread, finals, 0, 1);
  // qkv = dequant(q(hbuf) @ qkv_wq^T) + b -> big (f16); A quantized in-staging
  gemm_q_t<0><<<dim3(18, 128), 512, 0, stream>>>(hbuf, 768, qkv_wq,
                                                 finals + 0, finals + 1,
                                                 qkv_b, nullptr, nullptr, big,
                                                 nullptr, 0, 2304, 768);
  // attention in place (o -> Q slice of big = first 768 cols, stride 2304)
  attn_k<<<6144, 256, 0, stream>>>(big, spread, 5);
  reduce_slots_k<<<1, 64, 0, stream>>>(spread, finals, 5, 1);
  // x2 = q(o) @ proj_wq^T + b + x -> out; A = big strided 2304
  gemm_q_t<2><<<dim3(6, 128), 512, 0, stream>>>(big, 2304, proj_wq,
                                                finals + 5, finals + 2,
                                                proj_b, x, out, nullptr,
                                                nullptr, 0, 768, 768);
  // LN2 -> hbuf + absmax slot 6
  ln_k<<<8192, 256, 0, stream>>>(out, ln2_g, ln2_b, hbuf, spread, 6);
  reduce_slots_k<<<1, 64, 0, stream>>>(spread, finals, 6, 1);
  // g = gelu(q(hbuf) @ fc1_wq^T + b) -> big (f16, 3072-wide) + absmax slot 7
  gemm_q_t<1><<<dim3(24, 128), 512, 0, stream>>>(hbuf, 768, fc1_wq,
                                                 finals + 6, finals + 3,
                                                 fc1_b, nullptr, nullptr, big,
                                                 spread, 7, 3072, 768);
  reduce_slots_k<<<1, 64, 0, stream>>>(spread, finals, 7, 1);
  // out = q(g) @ fc2_wq^T + b + x2 (in-place residual); A = big stride 3072
  gemm_q_t<2><<<dim3(6, 128), 512, 0, stream>>>(big, 3072, fc2_wq,
                                                finals + 7, finals + 4,
                                                fc2_b, out, out, nullptr,
                                                nullptr, 0, 768, 3072);
}

// Round 13
// 799.565 us; speedup vs baseline: 1.2874x; 1.2874x over previous
//
#include <hip/hip_runtime.h>
#include <cmath>
#include <cstdint>

typedef _Float16 f16;
typedef _Float16 half8 __attribute__((ext_vector_type(8)));
typedef _Float16 half4 __attribute__((ext_vector_type(4)));
typedef float f32x4 __attribute__((ext_vector_type(4)));
typedef int i32x4 __attribute__((ext_vector_type(4)));
typedef int8_t c8v __attribute__((ext_vector_type(8)));
typedef int8_t c4v __attribute__((ext_vector_type(4)));

#define M_TOTAL 32768     // B * C * T = 8 * 4096
#define D_MODEL 768
#define NE_TOT  25165824  // M_TOTAL * D_MODEL
#define SPREAD_STRIDE 16  // unsigneds between atomic cells (64 B: own cache line)

// ---------------------------------------------------------------- utilities

__device__ __forceinline__ void async_copy16(void* lds, const void* gmem) {
  __builtin_amdgcn_global_load_lds(
      (__attribute__((address_space(1))) void*)gmem,
      (__attribute__((address_space(3))) void*)lds, 16, 0, 0);
}

// gelu with A&S 7.1.26 erf approx: |erf err| <= 1.5e-7 (far below the f16
// rounding of the stored result). ~16 VALU ops vs ~35 for libm erff.
__device__ __forceinline__ float gelu_fast(float v) {
  float x = v * 0.70710678118654752f;
  float ax = fabsf(x);
  float t = __builtin_amdgcn_rcpf(fmaf(0.3275911f, ax, 1.0f));
  float y = t * (0.254829592f +
            t * (-0.284496736f +
            t * (1.421413741f +
            t * (-1.453152027f + t * 1.061405429f))));
  float e = __expf(-x * x);
  float erf_ax = fmaf(-y, e, 1.0f);
  float erf_x = copysignf(erf_ax, x);
  return 0.5f * v * (1.0f + erf_x);
}

__device__ __forceinline__ int8_t q8_val(float v, float s) {
  float q = fminf(fmaxf(rintf(v / s), -128.f), 127.f);
  return (int8_t)(int)q;
}

// NW-wave block max reduction
template <int NW>
__device__ __forceinline__ float block_reduce_max_t(float m) {
  __shared__ float red_brm[NW];
  for (int o = 32; o; o >>= 1) m = fmaxf(m, __shfl_down(m, o));
  int lane = threadIdx.x & 63, wv = threadIdx.x >> 6;
  if (lane == 0) red_brm[wv] = m;
  __syncthreads();
  float r = red_brm[0];
#pragma unroll
  for (int w = 1; w < NW; ++w) r = fmaxf(r, red_brm[w]);
  return r;
}

__device__ __forceinline__ unsigned* spread_cell(unsigned* spread, int slot,
                                                 int cell) {
  return spread + slot * 64 * SPREAD_STRIDE + (cell & 63) * SPREAD_STRIDE;
}

// self-reduce a spread slot's 64 cells -> per-tensor int8 scale. One load +
// 6 shuffles per wave; replaces the former 1-block reduce_slots launches
// (5 of them) whose launch+serialization cost exceeded this by ~100x.
// Requires all 64 lanes of the calling wave active.
__device__ __forceinline__ float spread_scale(const unsigned* spread,
                                              int slot) {
  int lane = threadIdx.x & 63;
  float m = __uint_as_float(
      spread[slot * 64 * SPREAD_STRIDE + lane * SPREAD_STRIDE]);
#pragma unroll
  for (int o = 32; o; o >>= 1) m = fmaxf(m, __shfl_xor(m, o));
  return fmaxf(m, 1e-8f) / 127.0f;
}

// XCD-chunked bijective swizzle (requires nwg % 8 == 0 — all our grids are).
__device__ __forceinline__ int xcd_swizzle(int lin, int nwg) {
  return (lin & 7) * (nwg >> 3) + (lin >> 3);
}

// 16 residual loads (4 rows x 4 col-tiles) into named registers — issued
// back-to-back so they batch in the memory pipe. Caller software-pipelines
// these ahead of the stores (resid may alias outf: fc2 is in-place, so no
// __restrict__ — batching must be structural, not alias-based).
__device__ __forceinline__ void load_resid16(const float* resid, int N,
                                             int r0, int c0, float* rv) {
#pragma unroll
  for (int j = 0; j < 4; ++j)
#pragma unroll
    for (int reg = 0; reg < 4; ++reg)
      rv[j * 4 + reg] = resid[(size_t)(r0 + reg) * N + c0 + j * 16];
}

// ---------------------------------------------------------------- small kernels

__global__ void zero_spread_k(unsigned* s) {
  int i = blockIdx.x * blockDim.x + threadIdx.x;
  if (i < 8 * 64 * SPREAD_STRIDE) s[i] = 0u;
}

// all 4 weight absmaxes in ONE launch: blockIdx.y = tensor id -> slot 1+y
__global__ __launch_bounds__(256) void absmax4_k(
    const float* __restrict__ w0, const float* __restrict__ w1,
    const float* __restrict__ w2, const float* __restrict__ w3,
    unsigned* spread) {
  const float* xs[4] = {w0, w1, w2, w3};
  const int n4s[4] = {442368, 147456, 589824, 589824};
  int ty = blockIdx.y;
  const float4* x4 = (const float4*)xs[ty];
  int n4 = n4s[ty];
  int i = blockIdx.x * blockDim.x + threadIdx.x;
  int stride = gridDim.x * blockDim.x;
  float m = 0.f;
  for (; i < n4; i += stride) {
    float4 v = x4[i];
    m = fmaxf(m, fmaxf(fmaxf(fabsf(v.x), fabsf(v.y)),
                       fmaxf(fabsf(v.z), fabsf(v.w))));
  }
  m = block_reduce_max_t<4>(m);
  if (threadIdx.x == 0)
    atomicMax(spread_cell(spread, 1 + ty, blockIdx.x), __float_as_uint(m));
}

// weights: f32 -> int8 (4/thread); scale self-reduced from spread slot
__global__ void quant_w8_k(const float* __restrict__ x, int n4,
                           const unsigned* __restrict__ spread, int slot,
                           int8_t* __restrict__ out) {
  float s = spread_scale(spread, slot);
  int i = blockIdx.x * blockDim.x + threadIdx.x;
  if (i >= n4) return;
  float4 v = ((const float4*)x)[i];
  c4v q = {q8_val(v.x, s), q8_val(v.y, s), q8_val(v.z, s), q8_val(v.w, s)};
  ((c4v*)out)[i] = q;
}

// LayerNorm: wave-per-row (4 rows/block), float4 loads (16 B/lane), half4
// stores, wave-only butterfly reductions — no LDS, no __syncthreads.
__global__ __launch_bounds__(256) void ln_k(const float* __restrict__ x,
                                            const float* __restrict__ gw,
                                            const float* __restrict__ bw,
                                            f16* __restrict__ out,
                                            unsigned* spread, int slot) {
  int tid = threadIdx.x, lane = tid & 63, wv = tid >> 6;
  int row = blockIdx.x * 4 + wv;
  const float4* xr = (const float4*)(x + (size_t)row * D_MODEL);
  float4 v[3];
  float s = 0.f, ss = 0.f;
#pragma unroll
  for (int j = 0; j < 3; ++j) {
    v[j] = xr[lane + j * 64];
    s += v[j].x + v[j].y + v[j].z + v[j].w;
    ss += v[j].x * v[j].x + v[j].y * v[j].y + v[j].z * v[j].z +
          v[j].w * v[j].w;
  }
#pragma unroll
  for (int o = 32; o; o >>= 1) {
    s += __shfl_xor(s, o);
    ss += __shfl_xor(ss, o);
  }
  float mean = s * (1.f / 768.f);
  float var = ss * (1.f / 768.f) - mean * mean;
  float rstd = rsqrtf(var + 1e-5f);
  const float4* g4 = (const float4*)gw;
  const float4* b4 = (const float4*)bw;
  f16* outr = out + (size_t)row * D_MODEL;
  float m = 0.f;
#pragma unroll
  for (int j = 0; j < 3; ++j) {
    float4 g = g4[lane + j * 64], b = b4[lane + j * 64];
    float y0 = (v[j].x - mean) * rstd * g.x + b.x;
    float y1 = (v[j].y - mean) * rstd * g.y + b.y;
    float y2 = (v[j].z - mean) * rstd * g.z + b.z;
    float y3 = (v[j].w - mean) * rstd * g.w + b.w;
    half4 hq = {(f16)y0, (f16)y1, (f16)y2, (f16)y3};
    *(half4*)(outr + (size_t)(lane + j * 64) * 4) = hq;
    m = fmaxf(m, fmaxf(fmaxf(fabsf(y0), fabsf(y1)),
                       fmaxf(fabsf(y2), fabsf(y3))));
  }
#pragma unroll
  for (int o = 32; o; o >>= 1) m = fmaxf(m, __shfl_xor(m, o));
  if (lane == 0)
    atomicMax(spread_cell(spread, slot, blockIdx.x * 4 + wv),
              __float_as_uint(m));
}

// dense f16 -> int8, 8 elems/thread; scale self-reduced (grid exact: no
// inactive lanes at the wave shuffle)
__global__ void quant8_k(const f16* __restrict__ src, int n8,
                         const unsigned* __restrict__ spread, int slot,
                         int8_t* __restrict__ out) {
  float s = spread_scale(spread, slot);
  int i = blockIdx.x * blockDim.x + threadIdx.x;
  if (i >= n8) return;
  half8 v = ((const half8*)src)[i];
  c8v q;
#pragma unroll
  for (int j = 0; j < 8; ++j) q[j] = q8_val((float)v[j], s);
  ((c8v*)out)[i] = q;
}

// attention output: strided read of Q slice of qkv buffer -> dense int8
__global__ void quant_strided8_k(const f16* __restrict__ src,
                                 const unsigned* __restrict__ spread,
                                 int slot, int8_t* __restrict__ out) {
  float s = spread_scale(spread, slot);
  int i = blockIdx.x * blockDim.x + threadIdx.x;  // 8-elem groups
  if (i >= NE_TOT / 8) return;
  int row = i / 96, c8 = i - row * 96;
  half8 v = *(const half8*)(src + (size_t)row * 2304 + c8 * 8);
  c8v q;
#pragma unroll
  for (int j = 0; j < 8; ++j) q[j] = q8_val((float)v[j], s);
  ((c8v*)out)[i] = q;
}

// ---------------------------------------------------------------- int8 GEMM
// C[m,n] = (sum_k qA[m,k]*qB[n,k]) * sA*sB + bias[n] (+resid) (+gelu).
// r11-verified structure (807.9 us total; 0 bank conflicts, occupancy 40%):
// BM=256 x BN=128, 512 threads (8 waves, 4Mx2N), per-wave 64x64.
// LDS = 3 x (16 KB A + 8 KB B) = 72 KB -> 2 blocks/CU. Paired-row layout
// (pr=r>>1, 128-B rows, chunk (pr,sl) holds g=sl^(pr&7): row 2pr+(g>>2),
// k-chunk g&3); read slot ((r&1)<<2|q)^(pr&7) — measured 0 conflicts.
// 3-buffer depth-2 pipeline, counted s_waitcnt vmcnt(6)/3/0, raw s_barrier.
// r12 LESSON: do NOT put activation-quant VALU inside this loop (7x the
// MFMA work -> VALU-bound, fc1 155->287 us). Scales self-reduced from
// spread in the EPILOGUE (off the K-loop critical path).
// MODE: 0 = f16 out (qkv), 1 = gelu+f16+absmax (fc1), 2 = resid+f32 out
// (proj/fc2; fc2 aliases resid==outf, epilogue pipelines batched loads
// ahead of stores). Split so MODE 2's VGPRs don't cost MODE 0/1 occupancy.
template <int MODE>
__global__ __launch_bounds__(512) void gemm_i8_t(
    const int8_t* __restrict__ A, const int8_t* __restrict__ B,
    const unsigned* __restrict__ spread_r, int sA_slot, int sB_slot,
    const float* __restrict__ bias, const float* resid,
    float* outf, f16* outh, unsigned* spread_w, int out_slot,
    int N, int K) {
  __shared__ __attribute__((aligned(16))) int8_t sA[3][128 * 128];  // 256 A-rows
  __shared__ __attribute__((aligned(16))) int8_t sB[3][64 * 128];   // 128 B-rows
  int tid = threadIdx.x;
  int nwg = gridDim.x * gridDim.y;
  int lin = blockIdx.y * gridDim.x + blockIdx.x;
  int swz = xcd_swizzle(lin, nwg);
  int n0 = (swz % gridDim.x) * 128, m0 = (swz / gridDim.x) * 256;
  int lane = tid & 63, wv = tid >> 6;            // 8 waves
  int wm = (wv >> 1) * 64, wn = (wv & 1) * 64;   // 4M x 2N wave grid
  int lr = lane & 15, quad = lane >> 4;

  i32x4 acc[4][4];
#pragma unroll
  for (int i = 0; i < 4; ++i)
#pragma unroll
    for (int j = 0; j < 4; ++j) acc[i][j] = i32x4{0, 0, 0, 0};

  // ---- staging: A 1024 chunks (2/thread), B 512 chunks (1/thread).
  // chunk c=(pr,sl): g = sl^(pr&7) -> matrix row 2pr+(g>>2), k-chunk g&3.
  auto mkA = [&](int c) {
    int pr = c >> 3, sl = c & 7, g = sl ^ (pr & 7);
    return A + (size_t)(m0 + 2 * pr + (g >> 2)) * K + (g & 3) * 16;
  };
  auto mkB = [&](int c) {
    int pr = c >> 3, sl = c & 7, g = sl ^ (pr & 7);
    return B + (size_t)(n0 + 2 * pr + (g >> 2)) * K + (g & 3) * 16;
  };
  const int8_t* sa0 = mkA(tid);
  const int8_t* sa1 = mkA(512 + tid);
  const int8_t* sb0 = mkB(tid);
  int la0 = tid * 16, la1 = (512 + tid) * 16;
  auto stage = [&](int b) {
    async_copy16(&sA[b][la0], sa0);
    async_copy16(&sA[b][la1], sa1);
    async_copy16(&sB[b][la0], sb0);
    sa0 += 64;
    sa1 += 64;
    sb0 += 64;
  };

  // ---- hoisted LDS read offsets (paired-row layout inverse)
  int aoff[4], boff[4];
#pragma unroll
  for (int i = 0; i < 4; ++i) {
    int r = wm + i * 16 + lr, pr = r >> 1;
    aoff[i] = pr * 128 + (((((r & 1) << 2) | quad) ^ (pr & 7)) * 16);
    int rb = wn + i * 16 + lr, prb = rb >> 1;
    boff[i] = prb * 128 + (((((rb & 1) << 2) | quad) ^ (prb & 7)) * 16);
  }
  auto compute = [&](const int8_t* a_s, const int8_t* b_s) {
    i32x4 af[4], bfv[4];
#pragma unroll
    for (int i = 0; i < 4; ++i) af[i] = *(const i32x4*)&a_s[aoff[i]];
#pragma unroll
    for (int j = 0; j < 4; ++j) bfv[j] = *(const i32x4*)&b_s[boff[j]];
#pragma unroll
    for (int i = 0; i < 4; ++i)
#pragma unroll
      for (int j = 0; j < 4; ++j)
        acc[i][j] = __builtin_amdgcn_mfma_i32_16x16x64_i8(af[i], bfv[j],
                                                          acc[i][j], 0, 0, 0);
  };

  // ---- depth-2 pipeline over 3 rotating buffers (r8 schedule; 3 VMEM per
  // stage -> counted waits 6/3/0). nsteps even for all K (768->12, 3072->48).
  int bi0 = 0, bi1 = 1, bi2 = 2;
  stage(bi0);
  stage(bi1);
  int nsteps = K >> 6;
  int pairs = nsteps >> 1;
  for (int S = 0; S < pairs; ++S) {
    bool last = (S == pairs - 1);
    if (!last) {
      stage(bi2);
      asm volatile("s_waitcnt vmcnt(6)" ::: "memory");
    } else {
      asm volatile("s_waitcnt vmcnt(3)" ::: "memory");
    }
    __builtin_amdgcn_s_barrier();
    compute(sA[bi0], sB[bi0]);
    __builtin_amdgcn_s_barrier();
    if (!last) {
      stage(bi0);
      asm volatile("s_waitcnt vmcnt(6)" ::: "memory");
    } else {
      asm volatile("s_waitcnt vmcnt(0)" ::: "memory");
    }
    __builtin_amdgcn_s_barrier();
    compute(sA[bi1], sB[bi1]);
    __builtin_amdgcn_s_barrier();
    int t = bi0;  // (bi0,bi1,bi2) <- (bi2,bi0,bi1)
    bi0 = bi2;
    bi2 = bi1;
    bi1 = t;
  }

  // scales self-reduced here (off the K-loop; 2 loads + 12 shuffles)
  float scale = spread_scale(spread_r, sA_slot) *
                spread_scale(spread_r, sB_slot);
  int r0 = m0 + wm + quad * 4, c0 = n0 + wn + lr;
  float bv[4];
#pragma unroll
  for (int j = 0; j < 4; ++j) bv[j] = bias[c0 + j * 16];
  // epilogue: C/D layout col=lane&15, row=quad*4+reg
  if (MODE == 2) {
    // software-pipelined: batch i+1's 16 loads issue BEFORE batch i's stores,
    // so the alias-forced program order never serializes load latency.
    float rvA[16], rvB[16];
    load_resid16(resid, N, r0, c0, rvA);
#pragma unroll
    for (int i = 0; i < 4; ++i) {
      float* curv = (i & 1) ? rvB : rvA;   // static after full unroll
      float* nxt = (i & 1) ? rvA : rvB;
      if (i < 3) load_resid16(resid, N, r0 + (i + 1) * 16, c0, nxt);
#pragma unroll
      for (int j = 0; j < 4; ++j)
#pragma unroll
        for (int reg = 0; reg < 4; ++reg) {
          size_t idx = (size_t)(r0 + i * 16 + reg) * N + c0 + j * 16;
          outf[idx] = (float)acc[i][j][reg] * scale + bv[j] + curv[j * 4 + reg];
        }
    }
  } else if (MODE == 1) {
    float lmax = 0.f;
#pragma unroll
    for (int i = 0; i < 4; ++i)
#pragma unroll
      for (int j = 0; j < 4; ++j)
#pragma unroll
        for (int reg = 0; reg < 4; ++reg) {
          size_t idx = (size_t)(r0 + i * 16 + reg) * N + c0 + j * 16;
          float v = gelu_fast((float)acc[i][j][reg] * scale + bv[j]);
          lmax = fmaxf(lmax, fabsf(v));
          outh[idx] = (f16)v;
        }
    float bm = block_reduce_max_t<8>(lmax);
    if (tid == 0)
      atomicMax(spread_cell(spread_w, out_slot,
                            blockIdx.x + gridDim.x * blockIdx.y),
                __float_as_uint(bm));
  } else {
#pragma unroll
    for (int i = 0; i < 4; ++i)
#pragma unroll
      for (int j = 0; j < 4; ++j)
#pragma unroll
        for (int reg = 0; reg < 4; ++reg) {
          size_t idx = (size_t)(r0 + i * 16 + reg) * N + c0 + j * 16;
          outh[idx] = (f16)((float)acc[i][j][reg] * scale + bv[j]);
        }
  }
}

// ---------------------------------------------------------------- attention
// one block per (b,c,head). MFMA path: S = Q K^T (16x16x32 f16, wave = 16-row
// strip), register softmax (row lives on 16 lanes x 4 tiles), P -> LDS
// (C-layout -> A-layout transform), O = P V. O written over the Q slice.
__global__ __launch_bounds__(256) void attn_k(f16* __restrict__ qkv,
                                              unsigned* spread, int slot) {
  // stride 72 f16: rows stay 16B-aligned; ds_read_b128 fragments hit all 8
  // bank-phases evenly ((lr*9+quad)%8 uniform)
  __shared__ __attribute__((aligned(16))) f16 sQ[64 * 72];
  __shared__ __attribute__((aligned(16))) f16 sK[64 * 72];
  __shared__ __attribute__((aligned(16))) f16 sV[64 * 72];
  __shared__ __attribute__((aligned(16))) f16 sP[64 * 72];
  int tid = threadIdx.x, lane = tid & 63, wv = tid >> 6;
  int lr = lane & 15, quad = lane >> 4;
  int swz = xcd_swizzle(blockIdx.x, gridDim.x);  // 12 head-blocks of one
  int h = swz % 12, bc = swz / 12;               // (b,c) slab stay on one XCD
  size_t base = (size_t)bc * 64 * 2304;
  int qo = h * 64, ko = qo + 768, vo = qo + 1536;

#pragma unroll
  for (int p = 0; p < 2; ++p) {
    int idx = p * 256 + tid;     // 512 chunks of 8 f16
    int t = idx >> 3, d8 = idx & 7;
    size_t g = base + (size_t)t * 2304 + d8 * 8;
    *(half8*)&sQ[t * 72 + d8 * 8] = *(const half8*)(qkv + g + qo);
    *(half8*)&sK[t * 72 + d8 * 8] = *(const half8*)(qkv + g + ko);
    *(half8*)&sV[t * 72 + d8 * 8] = *(const half8*)(qkv + g + vo);
  }
  __syncthreads();

  // S = Q K^T: wave wv owns rows wv*16 .. wv*16+15; 4 col tiles j
  f32x4 acc[4];
#pragma unroll
  for (int j = 0; j < 4; ++j) acc[j] = f32x4{0.f, 0.f, 0.f, 0.f};
#pragma unroll
  for (int ks = 0; ks < 2; ++ks) {
    half8 aq = *(const half8*)&sQ[(wv * 16 + lr) * 72 + ks * 32 + quad * 8];
#pragma unroll
    for (int j = 0; j < 4; ++j) {
      half8 bk = *(const half8*)&sK[(j * 16 + lr) * 72 + ks * 32 + quad * 8];
      acc[j] = __builtin_amdgcn_mfma_f32_16x16x32_f16(aq, bk, acc[j], 0, 0, 0);
    }
  }

  // softmax: row (quad,reg) spans 16 lanes (lr) x 4 tiles (j)
  float pr[4][4];  // [j][reg]
#pragma unroll
  for (int reg = 0; reg < 4; ++reg) {
    float v0 = acc[0][reg] * 0.125f, v1 = acc[1][reg] * 0.125f;
    float v2 = acc[2][reg] * 0.125f, v3 = acc[3][reg] * 0.125f;
    float mx = fmaxf(fmaxf(v0, v1), fmaxf(v2, v3));
    for (int o = 8; o; o >>= 1) mx = fmaxf(mx, __shfl_xor(mx, o));
    float e0 = __expf(v0 - mx), e1 = __expf(v1 - mx);
    float e2 = __expf(v2 - mx), e3 = __expf(v3 - mx);
    float sum = e0 + e1 + e2 + e3;
    for (int o = 8; o; o >>= 1) sum += __shfl_xor(sum, o);
    float inv = 1.f / sum;
    pr[0][reg] = e0 * inv; pr[1][reg] = e1 * inv;
    pr[2][reg] = e2 * inv; pr[3][reg] = e3 * inv;
  }
  // P: C-layout -> natural row-major in LDS (scalar b16, ~2-way conflicts)
#pragma unroll
  for (int j = 0; j < 4; ++j)
#pragma unroll
    for (int reg = 0; reg < 4; ++reg)
      sP[(wv * 16 + quad * 4 + reg) * 72 + j * 16 + lr] = (f16)pr[j][reg];
  __syncthreads();

  // O = P V: A from sP rows (vector), B = V[s][d] column reads (scalar u16)
  f32x4 oacc[4];
#pragma unroll
  for (int j = 0; j < 4; ++j) oacc[j] = f32x4{0.f, 0.f, 0.f, 0.f};
#pragma unroll
  for (int ks = 0; ks < 2; ++ks) {
    half8 ap = *(const half8*)&sP[(wv * 16 + lr) * 72 + ks * 32 + quad * 8];
#pragma unroll
    for (int j = 0; j < 4; ++j) {
      half8 bv;
#pragma unroll
      for (int jj = 0; jj < 8; ++jj)
        bv[jj] = sV[(ks * 32 + quad * 8 + jj) * 72 + j * 16 + lr];
      oacc[j] = __builtin_amdgcn_mfma_f32_16x16x32_f16(ap, bv, oacc[j], 0, 0, 0);
    }
  }

  float lmax = 0.f;
#pragma unroll
  for (int j = 0; j < 4; ++j)
#pragma unroll
    for (int reg = 0; reg < 4; ++reg) {
      int m = wv * 16 + quad * 4 + reg;
      float v = oacc[j][reg];
      qkv[base + (size_t)m * 2304 + qo + j * 16 + lr] = (f16)v;
      lmax = fmaxf(lmax, fabsf(v));
    }
  lmax = block_reduce_max_t<4>(lmax);
  if (tid == 0)
    atomicMax(spread_cell(spread, slot, blockIdx.x), __float_as_uint(lmax));
}

// ---------------------------------------------------------------- launch

extern "C" void kernel_launch(void* const* d_in, const int* in_sizes, int n_in,
                              void* d_out, int out_size, void* d_ws,
                              size_t ws_size, hipStream_t stream) {
  (void)in_sizes; (void)n_in; (void)out_size; (void)ws_size;
  const float* x      = (const float*)d_in[0];
  const float* ln1_g  = (const float*)d_in[1];
  const float* ln1_b  = (const float*)d_in[2];
  const float* qkv_w  = (const float*)d_in[3];
  const float* qkv_b  = (const float*)d_in[4];
  const float* proj_w = (const float*)d_in[5];
  const float* proj_b = (const float*)d_in[6];
  const float* ln2_g  = (const float*)d_in[7];
  const float* ln2_b  = (const float*)d_in[8];
  const float* fc1_w  = (const float*)d_in[9];
  const float* fc1_b  = (const float*)d_in[10];
  const float* fc2_w  = (const float*)d_in[11];
  const float* fc2_b  = (const float*)d_in[12];
  float* out = (float*)d_out;

  char* ws = (char*)d_ws;
  unsigned* spread = (unsigned*)ws;                       // 8 x 64 cells x 64B
  int8_t* qkv_wq  = (int8_t*)(ws + 33280);                // int8 weights
  int8_t* proj_wq = qkv_wq + 1769472;
  int8_t* fc1_wq  = proj_wq + 589824;
  int8_t* fc2_wq  = fc1_wq + 2359296;
  // g_q region (96 MB) also hosts hbuf (f16, 48 MB) + a_i8 (24 MB): both are
  // dead by the time g_q is written (after fc1).
  int8_t* g_q  = fc2_wq + 2359296;
  f16*    hbuf = (f16*)g_q;                               // LN y (f16)
  int8_t* a_i8 = g_q + 50331648;                          // quantized acts
  f16*    big  = (f16*)(g_q + 100663296);                 // qkv / gelu f16
  // total ws use ~309 MB

  // 16 launches total (was 25): weight absmax fused 4->1; all 5 one-block
  // reduce_slots launches replaced by in-consumer wave self-reduction.
  zero_spread_k<<<(8 * 64 * SPREAD_STRIDE + 255) / 256, 256, 0, stream>>>(spread);
  absmax4_k<<<dim3(128, 4), 256, 0, stream>>>(qkv_w, proj_w, fc1_w, fc2_w, spread);
  quant_w8_k<<<(1769472 / 4 + 255) / 256, 256, 0, stream>>>(qkv_w, 1769472 / 4, spread, 1, qkv_wq);
  quant_w8_k<<<(589824 / 4 + 255) / 256, 256, 0, stream>>>(proj_w, 589824 / 4, spread, 2, proj_wq);
  quant_w8_k<<<(2359296 / 4 + 255) / 256, 256, 0, stream>>>(fc1_w, 2359296 / 4, spread, 3, fc1_wq);
  quant_w8_k<<<(2359296 / 4 + 255) / 256, 256, 0, stream>>>(fc2_w, 2359296 / 4, spread, 4, fc2_wq);

  // LN1 -> hbuf (f16) + absmax slot 0; quantize -> a_i8
  ln_k<<<8192, 256, 0, stream>>>(x, ln1_g, ln1_b, hbuf, spread, 0);
  quant8_k<<<NE_TOT / 8 / 256, 256, 0, stream>>>(hbuf, NE_TOT / 8, spread, 0, a_i8);
  // qkv = dequant(a_q @ qkv_wq^T) + b -> big (f16)
  gemm_i8_t<0><<<dim3(18, 128), 512, 0, stream>>>(a_i8, qkv_wq, spread, 0, 1,
                                                  qkv_b, nullptr, nullptr, big,
                                                  nullptr, 0, 2304, 768);
  // attention in place (o -> Q slice of big); absmax slot 5
  attn_k<<<6144, 256, 0, stream>>>(big, spread, 5);
  // fq(o) -> a_i8
  quant_strided8_k<<<NE_TOT / 8 / 256, 256, 0, stream>>>(big, spread, 5, a_i8);
  // x2 = o_q @ proj_wq^T + b + x -> out
  gemm_i8_t<2><<<dim3(6, 128), 512, 0, stream>>>(a_i8, proj_wq, spread, 5, 2,
                                                 proj_b, x, out, nullptr,
                                                 nullptr, 0, 768, 768);
  // LN2 -> hbuf + absmax slot 6; quantize -> a_i8
  ln_k<<<8192, 256, 0, stream>>>(out, ln2_g, ln2_b, hbuf, spread, 6);
  quant8_k<<<NE_TOT / 8 / 256, 256, 0, stream>>>(hbuf, NE_TOT / 8, spread, 6, a_i8);
  // g = gelu(h_q @ fc1_wq^T + b) -> big (f16) + absmax slot 7
  gemm_i8_t<1><<<dim3(24, 128), 512, 0, stream>>>(a_i8, fc1_wq, spread, 6, 3,
                                                  fc1_b, nullptr, nullptr, big,
                                                  spread, 7, 3072, 768);
  // fq(g) -> g_q (int8; overwrites dead hbuf/a_i8)
  quant8_k<<<100663296 / 8 / 256, 256, 0, stream>>>(big, 100663296 / 8, spread, 7, g_q);
  // out = g_q @ fc2_wq^T + b + x2 (in-place residual)
  gemm_i8_t<2><<<dim3(6, 128), 512, 0, stream>>>(g_q, fc2_wq, spread, 7, 4,
                                                 fc2_b, out, out, nullptr,
                                                 nullptr, 0, 768, 3072);
}